// Round 1
// baseline (74.374 us; speedup 1.0000x reference)
//
#include <hip/hip_runtime.h>

#define EPS 1e-5f

// ---------------- Pass 1: sum of squares of raw input (Parseval shortcut) ----
// 2048 blocks x 256 threads x 16 float4 = 33554432 floats exactly.
__global__ __launch_bounds__(256) void sumsq_kernel(const float4* __restrict__ x4,
                                                    float* __restrict__ partial) {
    __shared__ float sbuf[4];
    const int t = threadIdx.x;
    const size_t base = (size_t)blockIdx.x * 4096 + t;
    float s = 0.f;
#pragma unroll
    for (int k = 0; k < 16; ++k) {
        float4 v = x4[base + (size_t)k * 256];
        s += v.x * v.x + v.y * v.y + v.z * v.z + v.w * v.w;
    }
#pragma unroll
    for (int off = 32; off >= 1; off >>= 1) s += __shfl_down(s, off, 64);
    if ((t & 63) == 0) sbuf[t >> 6] = s;
    __syncthreads();
    if (t == 0) partial[blockIdx.x] = sbuf[0] + sbuf[1] + sbuf[2] + sbuf[3];
}

// ---------------- Pass 2: reduce partials -> scale ---------------------------
__global__ __launch_bounds__(256) void finalize_kernel(const float* __restrict__ partial,
                                                       float* __restrict__ scale) {
    __shared__ float sbuf[4];
    const int t = threadIdx.x;
    float s = 0.f;
#pragma unroll
    for (int k = 0; k < 8; ++k) s += partial[t + k * 256];
#pragma unroll
    for (int off = 32; off >= 1; off >>= 1) s += __shfl_down(s, off, 64);
    if ((t & 63) == 0) sbuf[t >> 6] = s;
    __syncthreads();
    if (t == 0) {
        const float total = sbuf[0] + sbuf[1] + sbuf[2] + sbuf[3];
        // mean(x_trans^2) = 1024 * total / 33554432 = total / 32768
        const float mean_trans = total * (1.0f / 32768.0f);
        const float alpha = sqrtf(mean_trans + EPS);
        scale[0] = 1.0f / (alpha + EPS);
    }
}

// ---------------- Pass 3: golay-modulate + FWHT-1024 + scale -----------------
// One wave (64 lanes) per row; 4 rows per 256-thread block.
// Lane l owns elements [l*16, l*16+16): bits 0-3 in-register, bits 4-9 via shfl_xor.
__global__ __launch_bounds__(256) void fwht_kernel(const float4* __restrict__ x4,
                                                   const float4* __restrict__ g4,
                                                   const float* __restrict__ scale,
                                                   float4* __restrict__ out4) {
    const int lane = threadIdx.x & 63;
    const int wid = threadIdx.x >> 6;
    const size_t row = (size_t)blockIdx.x * 4 + wid;
    const float4* xr = x4 + row * 256;  // 1024 floats = 256 float4
    float4* orow = (float4*)(out4 + row * 256);

    float e[16];
#pragma unroll
    for (int q = 0; q < 4; ++q) {
        float4 v = xr[lane * 4 + q];
        float4 g = g4[lane * 4 + q];
        e[q * 4 + 0] = v.x * g.x;
        e[q * 4 + 1] = v.y * g.y;
        e[q * 4 + 2] = v.z * g.z;
        e[q * 4 + 3] = v.w * g.w;
    }

    // In-register FWHT over bits 0-3 (butterfly stages commute bit-by-bit).
#pragma unroll
    for (int h = 1; h < 16; h <<= 1) {
#pragma unroll
        for (int i = 0; i < 16; ++i) {
            if (!(i & h)) {
                const float a = e[i], b = e[i | h];
                e[i] = a + b;
                e[i | h] = a - b;
            }
        }
    }

    // Cross-lane FWHT over bits 4-9 (lane bits 0-5).
#pragma unroll
    for (int m = 1; m <= 32; m <<= 1) {
        const bool up = (lane & m) != 0;
#pragma unroll
        for (int i = 0; i < 16; ++i) {
            const float t = __shfl_xor(e[i], m, 64);
            e[i] = up ? (t - e[i]) : (e[i] + t);
        }
    }

    const float s = scale[0];
#pragma unroll
    for (int q = 0; q < 4; ++q) {
        float4 v;
        v.x = e[q * 4 + 0] * s;
        v.y = e[q * 4 + 1] * s;
        v.z = e[q * 4 + 2] * s;
        v.w = e[q * 4 + 3] * s;
        orow[lane * 4 + q] = v;
    }
}

extern "C" void kernel_launch(void* const* d_in, const int* in_sizes, int n_in,
                              void* d_out, int out_size, void* d_ws, size_t ws_size,
                              hipStream_t stream) {
    const float* x = (const float*)d_in[0];
    const float* golay = (const float*)d_in[1];
    float* out = (float*)d_out;
    float* ws = (float*)d_ws;
    float* partial = ws;         // 2048 floats
    float* scale = ws + 2048;    // 1 float

    sumsq_kernel<<<2048, 256, 0, stream>>>((const float4*)x, partial);
    finalize_kernel<<<1, 256, 0, stream>>>(partial, scale);
    fwht_kernel<<<8192, 256, 0, stream>>>((const float4*)x, (const float4*)golay,
                                          scale, (float4*)out);
}